// Round 14
// baseline (291.118 us; speedup 1.0000x reference)
//
#include <hip/hip_runtime.h>
#include <hip/hip_bf16.h>
#include <cstddef>
#include <cstdint>

#define DIM 128
#define SCAN_CHUNK 2048   // 256 threads x 8 elems

typedef __attribute__((ext_vector_type(8))) short short8v;  // 8 bf16 (4 VGPR)
typedef __attribute__((ext_vector_type(4))) float f32x4;    // MFMA acc

__device__ __forceinline__ float leaky(float v) {
    return v > 0.0f ? v : 0.01f * v;
}

__device__ __forceinline__ unsigned short f2bf(float f) {
    unsigned u = __builtin_bit_cast(unsigned, f);
    u += 0x7FFF + ((u >> 16) & 1);      // round-to-nearest-even
    return (unsigned short)(u >> 16);
}

// pack two f32 -> one u32 of 2 bf16 (lo = a, hi = b), single HW instr
__device__ __forceinline__ unsigned cvt_pk_bf16(float a, float b) {
    unsigned r;
    asm("v_cvt_pk_bf16_f32 %0, %1, %2" : "=v"(r) : "v"(a), "v"(b));
    return r;
}

__device__ __forceinline__ float bf2f_hi(unsigned p) {
    return __builtin_bit_cast(float, p & 0xFFFF0000u);
}
__device__ __forceinline__ float bf2f_lo(unsigned p) {
    return __builtin_bit_cast(float, p << 16);
}

// async global->LDS, 16 B per lane; LDS dest = wave-uniform base + lane*16
__device__ __forceinline__ void gload_lds16(const float* g, float* lds) {
    __builtin_amdgcn_global_load_lds(
        (const __attribute__((address_space(1))) unsigned int*)g,
        (__attribute__((address_space(3))) unsigned int*)lds, 16, 0, 0);
}

// ---------------------------------------------------------------------------
// histogram of in-degree counts  +  W transpose/convert (first 16384 threads)
// (cnt zeroed by hipMemsetAsync before this launch)
// ---------------------------------------------------------------------------
__global__ __launch_bounds__(256)
void hist_kernel(const int* __restrict__ col, int* __restrict__ cnt, int E,
                 const float* __restrict__ Wg, const float* __restrict__ Wf,
                 unsigned short* __restrict__ WgT, unsigned short* __restrict__ WfT) {
    int gid = blockIdx.x * blockDim.x + threadIdx.x;
    if (gid < 128 * 128) {
        int c = gid >> 7, k = gid & 127;
        WgT[c * 128 + k] = f2bf(Wg[k * 128 + c]);
        WfT[c * 128 + k] = f2bf(Wf[k * 128 + c]);
    }
    if (gid < E) atomicAdd(&cnt[col[gid]], 1);
}

// ---------------------------------------------------------------------------
// Scan pass 1: per-chunk sums of cnt
// ---------------------------------------------------------------------------
__global__ __launch_bounds__(256)
void scan_block_sums(const int* __restrict__ cnt, int* __restrict__ bsum, int N) {
    __shared__ int sdata[4];
    int base = blockIdx.x * SCAN_CHUNK;
    int s = 0;
    for (int k = threadIdx.x; k < SCAN_CHUNK; k += 256) {
        int idx = base + k;
        s += (idx < N) ? cnt[idx] : 0;
    }
#pragma unroll
    for (int m = 1; m < 64; m <<= 1) s += __shfl_xor(s, m, 64);
    if ((threadIdx.x & 63) == 0) sdata[threadIdx.x >> 6] = s;
    __syncthreads();
    if (threadIdx.x == 0)
        bsum[blockIdx.x] = sdata[0] + sdata[1] + sdata[2] + sdata[3];
}

// ---------------------------------------------------------------------------
// Scan pass 2: exclusive scan of chunk sums (nb <= 128)
// ---------------------------------------------------------------------------
__global__ __launch_bounds__(128)
void scan_bsum_kernel(int* __restrict__ bsum, int nb) {
    __shared__ int wtot[2];
    int t = threadIdx.x;
    int lane = t & 63;
    int orig = (t < nb) ? bsum[t] : 0;
    int v = orig;
#pragma unroll
    for (int m = 1; m < 64; m <<= 1) {
        int u = __shfl_up(v, m, 64);
        if (lane >= m) v += u;
    }
    if (lane == 63) wtot[t >> 6] = v;
    __syncthreads();
    if (t >= 64) v += wtot[0];
    if (t < nb) bsum[t] = v - orig;   // exclusive
}

// ---------------------------------------------------------------------------
// Scan pass 3: exclusive scan -> off[0..N], cursor copy into cnt[]
// ---------------------------------------------------------------------------
__global__ __launch_bounds__(256)
void scan_write_kernel(int* __restrict__ cnt, const int* __restrict__ bsum,
                       int* __restrict__ off, int N) {
    __shared__ int wsum[4];
    int t = threadIdx.x;
    int base = blockIdx.x * SCAN_CHUNK + t * 8;
    int vals[8];
    int local = 0;
#pragma unroll
    for (int k = 0; k < 8; ++k) {
        int idx = base + k;
        int c = (idx < N) ? cnt[idx] : 0;
        vals[k] = local;
        local += c;
    }
    int tsum = local;
    int lane = t & 63;
    int v = tsum;
#pragma unroll
    for (int m = 1; m < 64; m <<= 1) {
        int u = __shfl_up(v, m, 64);
        if (lane >= m) v += u;
    }
    if (lane == 63) wsum[t >> 6] = v;
    __syncthreads();
    int woff = 0;
    for (int i = 0; i < (t >> 6); ++i) woff += wsum[i];
    int texcl = (v - tsum) + woff + bsum[blockIdx.x];
#pragma unroll
    for (int k = 0; k < 8; ++k) {
        int idx = base + k;
        int o = texcl + vals[k];
        if (idx <= N) off[idx] = o;
    }
    __syncthreads();
#pragma unroll
    for (int k = 0; k < 8; ++k) {
        int idx = base + k;
        int o = texcl + vals[k];
        if (idx < N) cnt[idx] = o;
    }
}

// ---------------------------------------------------------------------------
// Reorder edges into CSR-by-target, packed (row, weight) int2
// ---------------------------------------------------------------------------
__global__ __launch_bounds__(256)
void reorder_kernel(const int* __restrict__ row, const int* __restrict__ col,
                    const float* __restrict__ w, int* __restrict__ cursor,
                    int2* __restrict__ edgeRW, int E) {
    int e = blockIdx.x * blockDim.x + threadIdx.x;
    if (e < E) {
        int c = col[e];
        int pos = atomicAdd(&cursor[c], 1);
        edgeRW[pos] = make_int2(row[e], __builtin_bit_cast(int, w[e]));
    }
}

// ---------------------------------------------------------------------------
// PERSISTENT MFMA dual GEMM (R11 pipeline, 3-buffer / 3-blocks-per-CU).
// 768 blocks x 512 threads; block owns a CONTIGUOUS range of 32-row tiles.
// LDS: 3 x 16 KB f32 buffers -> ~50 KB/block -> 3 resident blocks/CU
// (24 waves/CU, was 16): +50% TLP against the latency wall R12 measured.
// Depth-2 prefetch, counted vmcnt (L=2,S=2 per tile, FIFO-accounted):
//   it0: vmcnt(2); it1: vmcnt(4); steady: vmcnt(6); last: vmcnt(4); never 0.
// dinv computed IN-PROLOGUE from CSR (replaces csr_dinv kernel); drained
// with vmcnt(0)+sched_barrier before any stage DMA to keep FIFO accounting.
// Permuted W columns: lane owns (row, 8 consecutive cols) -> 16 B stores.
//   hsb  = bf16(dinv*h) ; accb = bf16( leaky(f + bf) + bg + dinv*(dinv*h) )
// ---------------------------------------------------------------------------
__global__ __launch_bounds__(512, 6)
void gemm_mfma_kernel(const float* __restrict__ x_src, const float* __restrict__ x_tar,
                      int n_src, int n_total, int ntiles,
                      const int* __restrict__ off, const int2* __restrict__ edgeRW,
                      const unsigned short* __restrict__ WgT,
                      const unsigned short* __restrict__ WfT,
                      const float* __restrict__ bg, const float* __restrict__ bf,
                      unsigned short* __restrict__ hsb,
                      unsigned short* __restrict__ accb)
{
    __shared__ float Ash[3][32 * 128];   // 3 x 16 KB, 16B-chunk swizzled
    __shared__ float dinvS[320];         // dinv slice for this block's rows

    const int t    = threadIdx.x;
    const int lane = t & 63;
    const int wv   = t >> 6;          // 0..7
    const int h    = wv >> 2;         // row half (0..1): 16 rows
    const int q    = wv & 3;          // col quarter (0..3): 32 cols
    const int lr   = lane & 15;
    const int lk   = lane >> 4;

    // contiguous tile range for this block
    const int nb  = gridDim.x;
    const int K   = (ntiles + nb - 1) / nb;
    const int t0  = blockIdx.x * K;
    const int cnt = min(K, ntiles - t0);
    if (cnt <= 0) return;

    // ---- compute dinv slice from CSR (replaces csr_dinv kernel) ----
    for (int tt = t; tt < cnt * 32; tt += 512) {
        int gi = t0 * 32 + tt;
        if (gi >= n_total) gi = n_total - 1;
        int s0 = off[gi], e0 = off[gi + 1];
        float a = 1.0f;
        for (int j = s0; j < e0; ++j)
            a += __builtin_bit_cast(float, edgeRW[j].y);
        dinvS[tt] = rsqrtf(a);
    }
    asm volatile("s_waitcnt lgkmcnt(0)" ::: "memory");
    // drain all prologue vmem before any stage DMA (keeps FIFO accounting)
    __builtin_amdgcn_sched_barrier(0);
    asm volatile("s_waitcnt vmcnt(0)" ::: "memory");
    __builtin_amdgcn_sched_barrier(0);

    // ---- hoist W fragments + biases, PERMUTED columns ----
    short8v wg[4][2], wf[4][2];
#pragma unroll
    for (int ks = 0; ks < 4; ++ks)
#pragma unroll
        for (int nf = 0; nf < 2; ++nf) {
            int col = q * 32 + ((lr >> 2) << 3) + nf * 4 + (lr & 3);
            const size_t bo = (size_t)col * 128 + ks * 32 + lk * 8;
            wg[ks][nf] = *(const short8v*)(WgT + bo);
            wf[ks][nf] = *(const short8v*)(WfT + bo);
        }
    const int cb = q * 32 + lk * 8;
    float4 bgv[2], bfv[2];
#pragma unroll
    for (int nf = 0; nf < 2; ++nf) {
        bgv[nf] = *(const float4*)(bg + cb + nf * 4);
        bfv[nf] = *(const float4*)(bf + cb + nf * 4);
    }
    // drain W/bias loads too (issued after the explicit vmcnt(0))
    __builtin_amdgcn_sched_barrier(0);
    asm volatile("s_waitcnt vmcnt(0)" ::: "memory");
    __builtin_amdgcn_sched_barrier(0);

    // stage one 32-row tile: 1024 x 16B chunks / 512 threads = 2 DMA/thread
    auto stage = [&](int tl, int buf) {
#pragma unroll
        for (int s = 0; s < 2; ++s) {
            int id  = s * 512 + t;       // dest chunk id (linear)
            int row = id >> 5;           // 0..31
            int cs  = id & 31;
            int c   = cs ^ (row & 15);   // XOR-swizzled source chunk
            int rg  = tl * 32 + row;
            if (rg >= n_total) rg = n_total - 1;
            const float* xr = (rg < n_src) ? x_src + (size_t)rg * DIM
                                           : x_tar + (size_t)(rg - n_src) * DIM;
            gload_lds16(xr + c * 4, &Ash[buf][(size_t)(s * 512 + wv * 64) * 4]);
        }
    };

    // prologue: prefetch up to 2 tiles
    stage(t0, 0);
    if (1 < cnt) stage(t0 + 1, 1);

    const int xrow = h * 16 + lr;        // this lane's x row within tile
    const int xrs  = xrow & 15;

    int cur = 0;
    for (int it = 0; it < cnt; ++it) {
        // counted wait: drain exactly through this tile's 2 stage loads
        if (cnt >= 3) {
            if (it == 0)            asm volatile("s_waitcnt vmcnt(2)" ::: "memory");
            else if (it == 1)       asm volatile("s_waitcnt vmcnt(4)" ::: "memory");
            else if (it == cnt - 1) asm volatile("s_waitcnt vmcnt(4)" ::: "memory");
            else                    asm volatile("s_waitcnt vmcnt(6)" ::: "memory");
        } else {
            asm volatile("s_waitcnt vmcnt(0)" ::: "memory");
        }
        __builtin_amdgcn_sched_barrier(0);
        __builtin_amdgcn_s_barrier();
        __builtin_amdgcn_sched_barrier(0);

        if (it + 2 < cnt) {
            int b = cur + 2; if (b >= 3) b -= 3;
            stage(t0 + it + 2, b);
        }

        f32x4 accg[2], accf[2];
        accg[0] = (f32x4)0.0f; accg[1] = (f32x4)0.0f;
        accf[0] = (f32x4)0.0f; accf[1] = (f32x4)0.0f;

#pragma unroll
        for (int ks = 0; ks < 4; ++ks) {
            int c0 = ks * 8 + lk * 2;
            float4 q0 = *(const float4*)&Ash[cur][(size_t)(xrow * 32 + ( c0      ^ xrs)) * 4];
            float4 q1 = *(const float4*)&Ash[cur][(size_t)(xrow * 32 + ((c0 + 1) ^ xrs)) * 4];
            union { short8v v; unsigned u[4]; } cv;
            cv.u[0] = cvt_pk_bf16(q0.x, q0.y);
            cv.u[1] = cvt_pk_bf16(q0.z, q0.w);
            cv.u[2] = cvt_pk_bf16(q1.x, q1.y);
            cv.u[3] = cvt_pk_bf16(q1.z, q1.w);
#pragma unroll
            for (int nf = 0; nf < 2; ++nf) {
                accg[nf] = __builtin_amdgcn_mfma_f32_16x16x32_bf16(wg[ks][nf], cv.v, accg[nf], 0, 0, 0);
                accf[nf] = __builtin_amdgcn_mfma_f32_16x16x32_bf16(wf[ks][nf], cv.v, accf[nf], 0, 0, 0);
            }
        }

        // epilogue: lane owns (row r, cols cb..cb+7) -> ONE 16 B store/buffer
        const int tile = t0 + it;
        int r = tile * 32 + xrow;
        const bool valid = (r < n_total);
        float dv = dinvS[it * 32 + xrow];

        float hs[8], oo[8];
#pragma unroll
        for (int nf = 0; nf < 2; ++nf)
#pragma unroll
            for (int e = 0; e < 4; ++e) {
                int k = nf * 4 + e;
                hs[k] = dv * accg[nf][e];
                float f = accf[nf][e] + ((const float*)&bfv[nf])[e];
                oo[k] = leaky(f) + ((const float*)&bgv[nf])[e] + dv * hs[k];
            }

        uint4 hp, op;
        hp.x = cvt_pk_bf16(hs[0], hs[1]); hp.y = cvt_pk_bf16(hs[2], hs[3]);
        hp.z = cvt_pk_bf16(hs[4], hs[5]); hp.w = cvt_pk_bf16(hs[6], hs[7]);
        op.x = cvt_pk_bf16(oo[0], oo[1]); op.y = cvt_pk_bf16(oo[2], oo[3]);
        op.z = cvt_pk_bf16(oo[4], oo[5]); op.w = cvt_pk_bf16(oo[6], oo[7]);

        if (valid) {
            *(uint4*)(hsb  + (size_t)r * DIM + cb) = hp;
            *(uint4*)(accb + (size_t)r * DIM + cb) = op;
        }
        ++cur; if (cur == 3) cur = 0;
    }
}

// ---------------------------------------------------------------------------
// Gather + fused layernorm + leaky_relu.
// 4 nodes per wave: 16 lanes x 8 dims each (16B uint4 gathers), pipelined.
// dinv computed IN-LOOP from the weights it already traverses (no dinv buf).
//   out[i] = norm( accb[i] + dinv[i] * sum_{e->i} w_e * hsb[row_e] )
// ---------------------------------------------------------------------------
__global__ __launch_bounds__(256)
void gather_norm_kernel(const int* __restrict__ off, const int2* __restrict__ edgeRW,
                        const unsigned short* __restrict__ hsb,
                        const unsigned short* __restrict__ accb,
                        float* __restrict__ out, int n)
{
    const int wid  = threadIdx.x >> 6;
    const int lane = threadIdx.x & 63;
    const int sub  = lane >> 4;       // node within wave (0..3)
    const int sl   = lane & 15;       // lane within node, owns dims sl*8..+7
    int i = (blockIdx.x * 4 + wid) * 4 + sub;
    if (i >= n) i = n - 1;

    const int start = off[i];
    const int degc  = off[i + 1] - start;

    int md = degc;
    md = max(md, __shfl_xor(md, 16, 64));
    md = max(md, __shfl_xor(md, 32, 64));

    float s[8];
#pragma unroll
    for (int k = 0; k < 8; ++k) s[k] = 0.0f;
    float sw = 0.0f;                  // running sum of edge weights

    const unsigned short* gbase = hsb + (size_t)sl * 8;

    int   r0 = 0, r1 = 0;
    float w0 = 0.0f, w1 = 0.0f;
    if (0 < degc) { int2 m = edgeRW[start];     r0 = m.x; w0 = __builtin_bit_cast(float, m.y); }
    if (1 < degc) { int2 m = edgeRW[start + 1]; r1 = m.x; w1 = __builtin_bit_cast(float, m.y); }
    uint4 p0 = *(const uint4*)(gbase + (size_t)r0 * DIM);

    for (int t = 0; t < md; ++t) {
        uint4 p1 = p0;
        if (t + 1 < md)
            p1 = *(const uint4*)(gbase + (size_t)r1 * DIM);
        int r2 = 0; float w2 = 0.0f;
        if (t + 2 < md) {
            if (t + 2 < degc) {
                int2 m = edgeRW[start + t + 2];
                r2 = m.x; w2 = __builtin_bit_cast(float, m.y);
            }
        }
        sw += w0;
        s[0] += w0 * bf2f_lo(p0.x); s[1] += w0 * bf2f_hi(p0.x);
        s[2] += w0 * bf2f_lo(p0.y); s[3] += w0 * bf2f_hi(p0.y);
        s[4] += w0 * bf2f_lo(p0.z); s[5] += w0 * bf2f_hi(p0.z);
        s[6] += w0 * bf2f_lo(p0.w); s[7] += w0 * bf2f_hi(p0.w);
        p0 = p1;
        r0 = r1; w0 = w1;
        r1 = r2; w1 = w2;
    }

    const float dv = rsqrtf(1.0f + sw);     // self-loop weight 1 folded
    uint4 av = *(const uint4*)(accb + (size_t)i * DIM + sl * 8);
    float v[8];
    v[0] = bf2f_lo(av.x) + dv * s[0]; v[1] = bf2f_hi(av.x) + dv * s[1];
    v[2] = bf2f_lo(av.y) + dv * s[2]; v[3] = bf2f_hi(av.y) + dv * s[3];
    v[4] = bf2f_lo(av.z) + dv * s[4]; v[5] = bf2f_hi(av.z) + dv * s[5];
    v[6] = bf2f_lo(av.w) + dv * s[6]; v[7] = bf2f_hi(av.w) + dv * s[7];

    float sum = 0.0f;
#pragma unroll
    for (int k = 0; k < 8; ++k) sum += v[k];
#pragma unroll
    for (int m = 1; m < 16; m <<= 1) sum += __shfl_xor(sum, m, 64);
    const float mean = sum * (1.0f / 128.0f);

    float sq = 0.0f;
#pragma unroll
    for (int k = 0; k < 8; ++k) {
        v[k] -= mean;
        sq += v[k] * v[k];
    }
#pragma unroll
    for (int m = 1; m < 16; m <<= 1) sq += __shfl_xor(sq, m, 64);
    const float rstd = rsqrtf(sq * (1.0f / 128.0f) + 1e-6f);

    float4 o1, o2;
    o1.x = leaky(v[0] * rstd); o1.y = leaky(v[1] * rstd);
    o1.z = leaky(v[2] * rstd); o1.w = leaky(v[3] * rstd);
    o2.x = leaky(v[4] * rstd); o2.y = leaky(v[5] * rstd);
    o2.z = leaky(v[6] * rstd); o2.w = leaky(v[7] * rstd);
    float* op = out + (size_t)i * DIM + sl * 8;
    *(float4*)op       = o1;
    *(float4*)(op + 4) = o2;
}

// ---------------------------------------------------------------------------
extern "C" void kernel_launch(void* const* d_in, const int* in_sizes, int n_in,
                              void* d_out, int out_size, void* d_ws, size_t ws_size,
                              hipStream_t stream)
{
    const float* x_src = (const float*)d_in[0];
    const float* x_tar = (const float*)d_in[1];
    const int*   ei    = (const int*)d_in[2];
    const float* ew    = (const float*)d_in[3];
    const float* Wg    = (const float*)d_in[4];
    const float* bg    = (const float*)d_in[5];
    const float* Wf    = (const float*)d_in[6];
    const float* bf    = (const float*)d_in[7];

    const int n_src = in_sizes[0] / DIM;
    const int n_tar = in_sizes[1] / DIM;
    const int N     = n_src + n_tar;
    const int E     = in_sizes[3];

    const int* rowp = ei;       // edge_index[0] = message source
    const int* colp = ei + E;   // edge_index[1] = message target

    // ---- workspace layout ----
    char* p = (char*)d_ws;
    int*   cnt  = (int*)p;    p += (size_t)N * 4;
    int*   off  = (int*)p;    p += (size_t)(N + 1) * 4;
    int*   bsum = (int*)p;    p += 160 * 4;
    p = (char*)(((uintptr_t)p + 15) & ~(uintptr_t)15);
    int2*  edgeRW = (int2*)p; p += (size_t)E * 8;
    unsigned short* hsb  = (unsigned short*)p; p += (size_t)N * DIM * 2;
    unsigned short* accb = (unsigned short*)p; p += (size_t)N * DIM * 2;
    unsigned short* WgT  = (unsigned short*)p; p += 128 * 128 * 2;
    unsigned short* WfT  = (unsigned short*)p;

    const int NB = (N + 1 + SCAN_CHUNK - 1) / SCAN_CHUNK;

    hipMemsetAsync(cnt, 0, (size_t)N * sizeof(int), stream);

    hist_kernel<<<(E + 255) / 256, 256, 0, stream>>>(colp, cnt, E,
                                                     Wg, Wf, WgT, WfT);

    scan_block_sums<<<NB, 256, 0, stream>>>(cnt, bsum, N);
    scan_bsum_kernel<<<1, 128, 0, stream>>>(bsum, NB);
    scan_write_kernel<<<NB, 256, 0, stream>>>(cnt, bsum, off, N);

    reorder_kernel<<<(E + 255) / 256, 256, 0, stream>>>(rowp, colp, ew, cnt,
                                                        edgeRW, E);

    const int ntiles = (N + 31) / 32;
    gemm_mfma_kernel<<<768, 512, 0, stream>>>(
        x_src, x_tar, n_src, N, ntiles, off, edgeRW, WgT, WfT, bg, bf,
        hsb, accb);

    gather_norm_kernel<<<(N + 15) / 16, 256, 0, stream>>>(
        off, edgeRW, hsb, accb, (float*)d_out, N);
}

// Round 15
// 190.378 us; speedup vs baseline: 1.5292x; 1.5292x over previous
//
#include <hip/hip_runtime.h>
#include <hip/hip_bf16.h>
#include <cstddef>
#include <cstdint>

#define DIM 128
#define SCAN_CHUNK 2048   // 256 threads x 8 elems

typedef __attribute__((ext_vector_type(8))) short short8v;  // 8 bf16 (4 VGPR)
typedef __attribute__((ext_vector_type(4))) float f32x4;    // MFMA acc

__device__ __forceinline__ float leaky(float v) {
    return v > 0.0f ? v : 0.01f * v;
}

__device__ __forceinline__ unsigned short f2bf(float f) {
    unsigned u = __builtin_bit_cast(unsigned, f);
    u += 0x7FFF + ((u >> 16) & 1);      // round-to-nearest-even
    return (unsigned short)(u >> 16);
}

// pack two f32 -> one u32 of 2 bf16 (lo = a, hi = b), single HW instr
__device__ __forceinline__ unsigned cvt_pk_bf16(float a, float b) {
    unsigned r;
    asm("v_cvt_pk_bf16_f32 %0, %1, %2" : "=v"(r) : "v"(a), "v"(b));
    return r;
}

__device__ __forceinline__ float bf2f_hi(unsigned p) {
    return __builtin_bit_cast(float, p & 0xFFFF0000u);
}
__device__ __forceinline__ float bf2f_lo(unsigned p) {
    return __builtin_bit_cast(float, p << 16);
}

// async global->LDS, 16 B per lane; LDS dest = wave-uniform base + lane*16
__device__ __forceinline__ void gload_lds16(const float* g, float* lds) {
    __builtin_amdgcn_global_load_lds(
        (const __attribute__((address_space(1))) unsigned int*)g,
        (__attribute__((address_space(3))) unsigned int*)lds, 16, 0, 0);
}

// ---------------------------------------------------------------------------
// histogram of in-degree counts  +  W transpose/convert (first 16384 threads)
// (cnt zeroed by hipMemsetAsync before this launch)
// ---------------------------------------------------------------------------
__global__ __launch_bounds__(256)
void hist_kernel(const int* __restrict__ col, int* __restrict__ cnt, int E,
                 const float* __restrict__ Wg, const float* __restrict__ Wf,
                 unsigned short* __restrict__ WgT, unsigned short* __restrict__ WfT) {
    int gid = blockIdx.x * blockDim.x + threadIdx.x;
    if (gid < 128 * 128) {
        int c = gid >> 7, k = gid & 127;
        WgT[c * 128 + k] = f2bf(Wg[k * 128 + c]);
        WfT[c * 128 + k] = f2bf(Wf[k * 128 + c]);
    }
    if (gid < E) atomicAdd(&cnt[col[gid]], 1);
}

// ---------------------------------------------------------------------------
// Scan pass 1: per-chunk sums of cnt
// ---------------------------------------------------------------------------
__global__ __launch_bounds__(256)
void scan_block_sums(const int* __restrict__ cnt, int* __restrict__ bsum, int N) {
    __shared__ int sdata[4];
    int base = blockIdx.x * SCAN_CHUNK;
    int s = 0;
    for (int k = threadIdx.x; k < SCAN_CHUNK; k += 256) {
        int idx = base + k;
        s += (idx < N) ? cnt[idx] : 0;
    }
#pragma unroll
    for (int m = 1; m < 64; m <<= 1) s += __shfl_xor(s, m, 64);
    if ((threadIdx.x & 63) == 0) sdata[threadIdx.x >> 6] = s;
    __syncthreads();
    if (threadIdx.x == 0)
        bsum[blockIdx.x] = sdata[0] + sdata[1] + sdata[2] + sdata[3];
}

// ---------------------------------------------------------------------------
// Scan pass 2: exclusive scan of chunk sums (nb <= 128)
// ---------------------------------------------------------------------------
__global__ __launch_bounds__(128)
void scan_bsum_kernel(int* __restrict__ bsum, int nb) {
    __shared__ int wtot[2];
    int t = threadIdx.x;
    int lane = t & 63;
    int orig = (t < nb) ? bsum[t] : 0;
    int v = orig;
#pragma unroll
    for (int m = 1; m < 64; m <<= 1) {
        int u = __shfl_up(v, m, 64);
        if (lane >= m) v += u;
    }
    if (lane == 63) wtot[t >> 6] = v;
    __syncthreads();
    if (t >= 64) v += wtot[0];
    if (t < nb) bsum[t] = v - orig;   // exclusive
}

// ---------------------------------------------------------------------------
// Scan pass 3: exclusive scan -> off[0..N], cursor copy into cnt[]
// ---------------------------------------------------------------------------
__global__ __launch_bounds__(256)
void scan_write_kernel(int* __restrict__ cnt, const int* __restrict__ bsum,
                       int* __restrict__ off, int N) {
    __shared__ int wsum[4];
    int t = threadIdx.x;
    int base = blockIdx.x * SCAN_CHUNK + t * 8;
    int vals[8];
    int local = 0;
#pragma unroll
    for (int k = 0; k < 8; ++k) {
        int idx = base + k;
        int c = (idx < N) ? cnt[idx] : 0;
        vals[k] = local;
        local += c;
    }
    int tsum = local;
    int lane = t & 63;
    int v = tsum;
#pragma unroll
    for (int m = 1; m < 64; m <<= 1) {
        int u = __shfl_up(v, m, 64);
        if (lane >= m) v += u;
    }
    if (lane == 63) wsum[t >> 6] = v;
    __syncthreads();
    int woff = 0;
    for (int i = 0; i < (t >> 6); ++i) woff += wsum[i];
    int texcl = (v - tsum) + woff + bsum[blockIdx.x];
#pragma unroll
    for (int k = 0; k < 8; ++k) {
        int idx = base + k;
        int o = texcl + vals[k];
        if (idx <= N) off[idx] = o;
    }
    __syncthreads();
#pragma unroll
    for (int k = 0; k < 8; ++k) {
        int idx = base + k;
        int o = texcl + vals[k];
        if (idx < N) cnt[idx] = o;
    }
}

// ---------------------------------------------------------------------------
// Reorder edges into CSR-by-target, packed (row, weight) int2
// ---------------------------------------------------------------------------
__global__ __launch_bounds__(256)
void reorder_kernel(const int* __restrict__ row, const int* __restrict__ col,
                    const float* __restrict__ w, int* __restrict__ cursor,
                    int2* __restrict__ edgeRW, int E) {
    int e = blockIdx.x * blockDim.x + threadIdx.x;
    if (e < E) {
        int c = col[e];
        int pos = atomicAdd(&cursor[c], 1);
        edgeRW[pos] = make_int2(row[e], __builtin_bit_cast(int, w[e]));
    }
}

// ---------------------------------------------------------------------------
// PERSISTENT MFMA dual GEMM — R11 measured config restored EXACTLY:
// __launch_bounds__(512,4) (64 VGPR, NO SPILL — R14's (512,6) spilled W
// frags to scratch: FETCH 51->344 MB), 4 x 16 KB buffers, depth-3 prefetch,
// counted vmcnt ladder 4/6/8/10/8/6 (L=2,S=2 per tile FIFO; never 0),
// permuted W columns -> lane owns (row, 8 consecutive cols) -> 16 B stores.
// Kept from R14 (orthogonal to the spill): dinv computed IN-PROLOGUE from
// CSR (saves the csr_dinv launch), drained vmcnt(0)+sched_barrier before
// any stage DMA so the ladder's FIFO accounting holds.
//   hsb  = bf16(dinv*h) ; accb = bf16( leaky(f + bf) + bg + dinv*(dinv*h) )
// ---------------------------------------------------------------------------
__global__ __launch_bounds__(512, 4)
void gemm_mfma_kernel(const float* __restrict__ x_src, const float* __restrict__ x_tar,
                      int n_src, int n_total, int ntiles,
                      const int* __restrict__ off, const int2* __restrict__ edgeRW,
                      const unsigned short* __restrict__ WgT,
                      const unsigned short* __restrict__ WfT,
                      const float* __restrict__ bg, const float* __restrict__ bf,
                      unsigned short* __restrict__ hsb,
                      unsigned short* __restrict__ accb)
{
    __shared__ float Ash[4][32 * 128];   // 4 x 16 KB, 16B-chunk swizzled
    __shared__ float dinvS[448];         // dinv slice for this block's rows

    const int t    = threadIdx.x;
    const int lane = t & 63;
    const int wv   = t >> 6;          // 0..7
    const int h    = wv >> 2;         // row half (0..1): 16 rows
    const int q    = wv & 3;          // col quarter (0..3): 32 cols
    const int lr   = lane & 15;
    const int lk   = lane >> 4;

    // contiguous tile range for this block
    const int nb  = gridDim.x;
    const int K   = (ntiles + nb - 1) / nb;
    const int t0  = blockIdx.x * K;
    const int cnt = min(K, ntiles - t0);
    if (cnt <= 0) return;

    // ---- compute dinv slice from CSR (replaces csr_dinv kernel) ----
    for (int tt = t; tt < cnt * 32; tt += 512) {
        int gi = t0 * 32 + tt;
        if (gi >= n_total) gi = n_total - 1;
        int s0 = off[gi], e0 = off[gi + 1];
        float a = 1.0f;
        for (int j = s0; j < e0; ++j)
            a += __builtin_bit_cast(float, edgeRW[j].y);
        dinvS[tt] = rsqrtf(a);
    }
    asm volatile("s_waitcnt lgkmcnt(0)" ::: "memory");
    // drain all prologue vmem before any stage DMA (keeps FIFO accounting)
    __builtin_amdgcn_sched_barrier(0);
    asm volatile("s_waitcnt vmcnt(0)" ::: "memory");
    __builtin_amdgcn_sched_barrier(0);

    // ---- hoist W fragments + biases, PERMUTED columns ----
    short8v wg[4][2], wf[4][2];
#pragma unroll
    for (int ks = 0; ks < 4; ++ks)
#pragma unroll
        for (int nf = 0; nf < 2; ++nf) {
            int col = q * 32 + ((lr >> 2) << 3) + nf * 4 + (lr & 3);
            const size_t bo = (size_t)col * 128 + ks * 32 + lk * 8;
            wg[ks][nf] = *(const short8v*)(WgT + bo);
            wf[ks][nf] = *(const short8v*)(WfT + bo);
        }
    const int cb = q * 32 + lk * 8;
    float4 bgv[2], bfv[2];
#pragma unroll
    for (int nf = 0; nf < 2; ++nf) {
        bgv[nf] = *(const float4*)(bg + cb + nf * 4);
        bfv[nf] = *(const float4*)(bf + cb + nf * 4);
    }
    // drain W/bias loads too (issued after the explicit vmcnt(0))
    __builtin_amdgcn_sched_barrier(0);
    asm volatile("s_waitcnt vmcnt(0)" ::: "memory");
    __builtin_amdgcn_sched_barrier(0);

    // stage one 32-row tile: 1024 x 16B chunks / 512 threads = 2 DMA/thread
    auto stage = [&](int tl, int buf) {
#pragma unroll
        for (int s = 0; s < 2; ++s) {
            int id  = s * 512 + t;       // dest chunk id (linear)
            int row = id >> 5;           // 0..31
            int cs  = id & 31;
            int c   = cs ^ (row & 15);   // XOR-swizzled source chunk
            int rg  = tl * 32 + row;
            if (rg >= n_total) rg = n_total - 1;
            const float* xr = (rg < n_src) ? x_src + (size_t)rg * DIM
                                           : x_tar + (size_t)(rg - n_src) * DIM;
            gload_lds16(xr + c * 4, &Ash[buf][(size_t)(s * 512 + wv * 64) * 4]);
        }
    };

    // prologue: prefetch up to 3 tiles
    stage(t0, 0);
    if (1 < cnt) stage(t0 + 1, 1);
    if (2 < cnt) stage(t0 + 2, 2);

    const int xrow = h * 16 + lr;        // this lane's x row within tile
    const int xrs  = xrow & 15;

    for (int it = 0; it < cnt; ++it) {
        // counted wait: drain exactly through this tile's 2 stage loads
        if (cnt >= 6) {
            if (it == 0)              asm volatile("s_waitcnt vmcnt(4)"  ::: "memory");
            else if (it == 1)         asm volatile("s_waitcnt vmcnt(6)"  ::: "memory");
            else if (it == 2)         asm volatile("s_waitcnt vmcnt(8)"  ::: "memory");
            else if (it == cnt - 2)   asm volatile("s_waitcnt vmcnt(8)"  ::: "memory");
            else if (it == cnt - 1)   asm volatile("s_waitcnt vmcnt(6)"  ::: "memory");
            else                      asm volatile("s_waitcnt vmcnt(10)" ::: "memory");
        } else {
            asm volatile("s_waitcnt vmcnt(0)" ::: "memory");
        }
        __builtin_amdgcn_sched_barrier(0);
        __builtin_amdgcn_s_barrier();
        __builtin_amdgcn_sched_barrier(0);

        if (it + 3 < cnt) stage(t0 + it + 3, (it + 3) & 3);

        const int cur = it & 3;
        f32x4 accg[2], accf[2];
        accg[0] = (f32x4)0.0f; accg[1] = (f32x4)0.0f;
        accf[0] = (f32x4)0.0f; accf[1] = (f32x4)0.0f;

#pragma unroll
        for (int ks = 0; ks < 4; ++ks) {
            int c0 = ks * 8 + lk * 2;
            float4 q0 = *(const float4*)&Ash[cur][(size_t)(xrow * 32 + ( c0      ^ xrs)) * 4];
            float4 q1 = *(const float4*)&Ash[cur][(size_t)(xrow * 32 + ((c0 + 1) ^ xrs)) * 4];
            union { short8v v; unsigned u[4]; } cv;
            cv.u[0] = cvt_pk_bf16(q0.x, q0.y);
            cv.u[1] = cvt_pk_bf16(q0.z, q0.w);
            cv.u[2] = cvt_pk_bf16(q1.x, q1.y);
            cv.u[3] = cvt_pk_bf16(q1.z, q1.w);
#pragma unroll
            for (int nf = 0; nf < 2; ++nf) {
                accg[nf] = __builtin_amdgcn_mfma_f32_16x16x32_bf16(wg[ks][nf], cv.v, accg[nf], 0, 0, 0);
                accf[nf] = __builtin_amdgcn_mfma_f32_16x16x32_bf16(wf[ks][nf], cv.v, accf[nf], 0, 0, 0);
            }
        }

        // epilogue: lane owns (row r, cols cb..cb+7) -> ONE 16 B store/buffer
        const int tile = t0 + it;
        int r = tile * 32 + xrow;
        const bool valid = (r < n_total);
        float dv = dinvS[it * 32 + xrow];

        float hs[8], oo[8];
#pragma unroll
        for (int nf = 0; nf < 2; ++nf)
#pragma unroll
            for (int e = 0; e < 4; ++e) {
                int k = nf * 4 + e;
                hs[k] = dv * accg[nf][e];
                float f = accf[nf][e] + ((const float*)&bfv[nf])[e];
                oo[k] = leaky(f) + ((const float*)&bgv[nf])[e] + dv * hs[k];
            }

        uint4 hp, op;
        hp.x = cvt_pk_bf16(hs[0], hs[1]); hp.y = cvt_pk_bf16(hs[2], hs[3]);
        hp.z = cvt_pk_bf16(hs[4], hs[5]); hp.w = cvt_pk_bf16(hs[6], hs[7]);
        op.x = cvt_pk_bf16(oo[0], oo[1]); op.y = cvt_pk_bf16(oo[2], oo[3]);
        op.z = cvt_pk_bf16(oo[4], oo[5]); op.w = cvt_pk_bf16(oo[6], oo[7]);

        if (valid) {
            *(uint4*)(hsb  + (size_t)r * DIM + cb) = hp;
            *(uint4*)(accb + (size_t)r * DIM + cb) = op;
        }
    }
}

// ---------------------------------------------------------------------------
// Gather + fused layernorm + leaky_relu.
// 4 nodes per wave: 16 lanes x 8 dims each (16B uint4 gathers), pipelined.
// dinv computed IN-LOOP from the weights it already traverses (no dinv buf).
//   out[i] = norm( accb[i] + dinv[i] * sum_{e->i} w_e * hsb[row_e] )
// ---------------------------------------------------------------------------
__global__ __launch_bounds__(256)
void gather_norm_kernel(const int* __restrict__ off, const int2* __restrict__ edgeRW,
                        const unsigned short* __restrict__ hsb,
                        const unsigned short* __restrict__ accb,
                        float* __restrict__ out, int n)
{
    const int wid  = threadIdx.x >> 6;
    const int lane = threadIdx.x & 63;
    const int sub  = lane >> 4;       // node within wave (0..3)
    const int sl   = lane & 15;       // lane within node, owns dims sl*8..+7
    int i = (blockIdx.x * 4 + wid) * 4 + sub;
    if (i >= n) i = n - 1;

    const int start = off[i];
    const int degc  = off[i + 1] - start;

    int md = degc;
    md = max(md, __shfl_xor(md, 16, 64));
    md = max(md, __shfl_xor(md, 32, 64));

    float s[8];
#pragma unroll
    for (int k = 0; k < 8; ++k) s[k] = 0.0f;
    float sw = 0.0f;                  // running sum of edge weights

    const unsigned short* gbase = hsb + (size_t)sl * 8;

    int   r0 = 0, r1 = 0;
    float w0 = 0.0f, w1 = 0.0f;
    if (0 < degc) { int2 m = edgeRW[start];     r0 = m.x; w0 = __builtin_bit_cast(float, m.y); }
    if (1 < degc) { int2 m = edgeRW[start + 1]; r1 = m.x; w1 = __builtin_bit_cast(float, m.y); }
    uint4 p0 = *(const uint4*)(gbase + (size_t)r0 * DIM);

    for (int t = 0; t < md; ++t) {
        uint4 p1 = p0;
        if (t + 1 < md)
            p1 = *(const uint4*)(gbase + (size_t)r1 * DIM);
        int r2 = 0; float w2 = 0.0f;
        if (t + 2 < md) {
            if (t + 2 < degc) {
                int2 m = edgeRW[start + t + 2];
                r2 = m.x; w2 = __builtin_bit_cast(float, m.y);
            }
        }
        sw += w0;
        s[0] += w0 * bf2f_lo(p0.x); s[1] += w0 * bf2f_hi(p0.x);
        s[2] += w0 * bf2f_lo(p0.y); s[3] += w0 * bf2f_hi(p0.y);
        s[4] += w0 * bf2f_lo(p0.z); s[5] += w0 * bf2f_hi(p0.z);
        s[6] += w0 * bf2f_lo(p0.w); s[7] += w0 * bf2f_hi(p0.w);
        p0 = p1;
        r0 = r1; w0 = w1;
        r1 = r2; w1 = w2;
    }

    const float dv = rsqrtf(1.0f + sw);     // self-loop weight 1 folded
    uint4 av = *(const uint4*)(accb + (size_t)i * DIM + sl * 8);
    float v[8];
    v[0] = bf2f_lo(av.x) + dv * s[0]; v[1] = bf2f_hi(av.x) + dv * s[1];
    v[2] = bf2f_lo(av.y) + dv * s[2]; v[3] = bf2f_hi(av.y) + dv * s[3];
    v[4] = bf2f_lo(av.z) + dv * s[4]; v[5] = bf2f_hi(av.z) + dv * s[5];
    v[6] = bf2f_lo(av.w) + dv * s[6]; v[7] = bf2f_hi(av.w) + dv * s[7];

    float sum = 0.0f;
#pragma unroll
    for (int k = 0; k < 8; ++k) sum += v[k];
#pragma unroll
    for (int m = 1; m < 16; m <<= 1) sum += __shfl_xor(sum, m, 64);
    const float mean = sum * (1.0f / 128.0f);

    float sq = 0.0f;
#pragma unroll
    for (int k = 0; k < 8; ++k) {
        v[k] -= mean;
        sq += v[k] * v[k];
    }
#pragma unroll
    for (int m = 1; m < 16; m <<= 1) sq += __shfl_xor(sq, m, 64);
    const float rstd = rsqrtf(sq * (1.0f / 128.0f) + 1e-6f);

    float4 o1, o2;
    o1.x = leaky(v[0] * rstd); o1.y = leaky(v[1] * rstd);
    o1.z = leaky(v[2] * rstd); o1.w = leaky(v[3] * rstd);
    o2.x = leaky(v[4] * rstd); o2.y = leaky(v[5] * rstd);
    o2.z = leaky(v[6] * rstd); o2.w = leaky(v[7] * rstd);
    float* op = out + (size_t)i * DIM + sl * 8;
    *(float4*)op       = o1;
    *(float4*)(op + 4) = o2;
}

// ---------------------------------------------------------------------------
extern "C" void kernel_launch(void* const* d_in, const int* in_sizes, int n_in,
                              void* d_out, int out_size, void* d_ws, size_t ws_size,
                              hipStream_t stream)
{
    const float* x_src = (const float*)d_in[0];
    const float* x_tar = (const float*)d_in[1];
    const int*   ei    = (const int*)d_in[2];
    const float* ew    = (const float*)d_in[3];
    const float* Wg    = (const float*)d_in[4];
    const float* bg    = (const float*)d_in[5];
    const float* Wf    = (const float*)d_in[6];
    const float* bf    = (const float*)d_in[7];

    const int n_src = in_sizes[0] / DIM;
    const int n_tar = in_sizes[1] / DIM;
    const int N     = n_src + n_tar;
    const int E     = in_sizes[3];

    const int* rowp = ei;       // edge_index[0] = message source
    const int* colp = ei + E;   // edge_index[1] = message target

    // ---- workspace layout ----
    char* p = (char*)d_ws;
    int*   cnt  = (int*)p;    p += (size_t)N * 4;
    int*   off  = (int*)p;    p += (size_t)(N + 1) * 4;
    int*   bsum = (int*)p;    p += 160 * 4;
    p = (char*)(((uintptr_t)p + 15) & ~(uintptr_t)15);
    int2*  edgeRW = (int2*)p; p += (size_t)E * 8;
    unsigned short* hsb  = (unsigned short*)p; p += (size_t)N * DIM * 2;
    unsigned short* accb = (unsigned short*)p; p += (size_t)N * DIM * 2;
    unsigned short* WgT  = (unsigned short*)p; p += 128 * 128 * 2;
    unsigned short* WfT  = (unsigned short*)p;

    const int NB = (N + 1 + SCAN_CHUNK - 1) / SCAN_CHUNK;

    hipMemsetAsync(cnt, 0, (size_t)N * sizeof(int), stream);

    hist_kernel<<<(E + 255) / 256, 256, 0, stream>>>(colp, cnt, E,
                                                     Wg, Wf, WgT, WfT);

    scan_block_sums<<<NB, 256, 0, stream>>>(cnt, bsum, N);
    scan_bsum_kernel<<<1, 128, 0, stream>>>(bsum, NB);
    scan_write_kernel<<<NB, 256, 0, stream>>>(cnt, bsum, off, N);

    reorder_kernel<<<(E + 255) / 256, 256, 0, stream>>>(rowp, colp, ew, cnt,
                                                        edgeRW, E);

    const int ntiles = (N + 31) / 32;
    gemm_mfma_kernel<<<512, 512, 0, stream>>>(
        x_src, x_tar, n_src, N, ntiles, off, edgeRW, WgT, WfT, bg, bf,
        hsb, accb);

    gather_norm_kernel<<<(N + 15) / 16, 256, 0, stream>>>(
        off, edgeRW, hsb, accb, (float*)d_out, N);
}